// Round 1
// baseline (5794.152 us; speedup 1.0000x reference)
//
#include <hip/hip_runtime.h>

#define N_NODES 100000
#define N_EDGES 1600000
#define N_GRAPHS 256
#define F 128

// ---------------- degree (as float; exact for counts < 2^24) ----------------
__global__ __launch_bounds__(256) void deg_kernel(const int* __restrict__ dst,
                                                  float* __restrict__ deg) {
    int e = blockIdx.x * 256 + threadIdx.x;
    if (e < N_EDGES) atomicAdd(&deg[dst[e]], 1.0f);
}

__global__ __launch_bounds__(256) void dinv_kernel(float* __restrict__ deg) {
    int i = blockIdx.x * 256 + threadIdx.x;
    if (i < N_NODES) deg[i] = rsqrtf(deg[i] + 1.0f);
}

// ---------------- GEMM: H[N,128] = X[N,128] @ W[128,128] --------------------
// block = 256 threads, 16 rows/block. W staged in K-halves (32KB), X tile
// padded to 132 floats/row so the 4-distinct-row broadcast read is
// conflict-free (132 % 32 = 4 -> rows land in different banks).
#define GROWS 16
__global__ __launch_bounds__(256) void gemm_kernel(const float* __restrict__ X,
                                                   const float* __restrict__ W,
                                                   float* __restrict__ H) {
    __shared__ float Wl[64 * 128];
    __shared__ float Xl[GROWS * 132];
    const int tid = threadIdx.x;
    const int row0 = blockIdx.x * GROWS;

    // load X tile (2048 floats, float4-coalesced)
    for (int i = tid * 4; i < GROWS * 128; i += 256 * 4) {
        int r = i >> 7, k = i & 127;
        *(float4*)&Xl[r * 132 + k] = *(const float4*)&X[(row0 + r) * 128 + k];
    }

    const int r  = tid >> 4;          // 0..15
    const int c0 = (tid & 15) * 8;    // 0,8,...,120
    float acc[8];
#pragma unroll
    for (int i = 0; i < 8; ++i) acc[i] = 0.0f;

    for (int kb = 0; kb < 128; kb += 64) {
        __syncthreads();
        // load W[kb..kb+64) rows (8192 floats)
        for (int i = tid * 4; i < 64 * 128; i += 256 * 4) {
            *(float4*)&Wl[i] = *(const float4*)&W[kb * 128 + i];
        }
        __syncthreads();
#pragma unroll 8
        for (int k = 0; k < 64; ++k) {
            float xv = Xl[r * 132 + kb + k];
            float4 wa = *(float4*)&Wl[k * 128 + c0];
            float4 wb = *(float4*)&Wl[k * 128 + c0 + 4];
            acc[0] += xv * wa.x; acc[1] += xv * wa.y;
            acc[2] += xv * wa.z; acc[3] += xv * wa.w;
            acc[4] += xv * wb.x; acc[5] += xv * wb.y;
            acc[6] += xv * wb.z; acc[7] += xv * wb.w;
        }
    }
    float* o = &H[(row0 + r) * 128 + c0];
    *(float4*)&o[0] = make_float4(acc[0], acc[1], acc[2], acc[3]);
    *(float4*)&o[4] = make_float4(acc[4], acc[5], acc[6], acc[7]);
}

// ---------------- edge scatter: AGG[dst] += H[src] * dinv[s]*dinv[d] --------
// 32 threads per edge, float4 per thread.
__global__ __launch_bounds__(256) void scatter_kernel(const int* __restrict__ src,
                                                      const int* __restrict__ dst,
                                                      const float* __restrict__ dinv,
                                                      const float* __restrict__ H,
                                                      float* __restrict__ AGG) {
    long long t = (long long)blockIdx.x * 256 + threadIdx.x;
    int e = (int)(t >> 5);
    if (e >= N_EDGES) return;
    int f = ((int)t & 31) * 4;
    int s = src[e], d = dst[e];
    float norm = dinv[s] * dinv[d];
    float4 v = *(const float4*)&H[s * 128 + f];
    float* a = &AGG[d * 128 + f];
    atomicAdd(a + 0, v.x * norm);
    atomicAdd(a + 1, v.y * norm);
    atomicAdd(a + 2, v.z * norm);
    atomicAdd(a + 3, v.w * norm);
}

// ---------------- epilogue: Y = relu(AGG + H*dinv^2 + b), in-place in AGG ---
__global__ __launch_bounds__(256) void epilogue_kernel(const float* __restrict__ H,
                                                       const float* __restrict__ dinv,
                                                       const float* __restrict__ b,
                                                       float* __restrict__ AGG) {
    int t = blockIdx.x * 256 + threadIdx.x;      // float4 index
    if (t >= N_NODES * 32) return;
    int n = t >> 5;
    int f = (t & 31) * 4;
    float di = dinv[n];
    float sl = di * di;
    float4 h = *(const float4*)&H[n * 128 + f];
    float4 a = *(float4*)&AGG[n * 128 + f];
    float4 bb = *(const float4*)&b[f];
    float4 o;
    o.x = fmaxf(a.x + h.x * sl + bb.x, 0.0f);
    o.y = fmaxf(a.y + h.y * sl + bb.y, 0.0f);
    o.z = fmaxf(a.z + h.z * sl + bb.z, 0.0f);
    o.w = fmaxf(a.w + h.w * sl + bb.w, 0.0f);
    *(float4*)&AGG[n * 128 + f] = o;
}

// ---------------- mean-pool: run-length accumulate over sorted batch --------
#define NODES_PER_GROUP 100
__global__ __launch_bounds__(256) void pool_kernel(const float* __restrict__ Y,
                                                   const int* __restrict__ batch,
                                                   float* __restrict__ pooled,
                                                   float* __restrict__ counts) {
    int g = (blockIdx.x * 256 + threadIdx.x) >> 5;   // 32-thread group id
    int lane = threadIdx.x & 31;
    int f = lane * 4;
    int n0 = g * NODES_PER_GROUP;
    if (n0 >= N_NODES) return;
    int n1 = min(n0 + NODES_PER_GROUP, N_NODES);
    int cur = batch[n0];
    float4 acc = make_float4(0, 0, 0, 0);
    float cnt = 0.0f;
    for (int n = n0; n < n1; ++n) {
        int bid = batch[n];
        if (bid != cur) {
            float* p = &pooled[cur * 128 + f];
            atomicAdd(p + 0, acc.x); atomicAdd(p + 1, acc.y);
            atomicAdd(p + 2, acc.z); atomicAdd(p + 3, acc.w);
            if (lane == 0) atomicAdd(&counts[cur], cnt);
            acc = make_float4(0, 0, 0, 0); cnt = 0.0f; cur = bid;
        }
        float4 v = *(const float4*)&Y[n * 128 + f];
        acc.x += v.x; acc.y += v.y; acc.z += v.z; acc.w += v.w;
        cnt += 1.0f;
    }
    float* p = &pooled[cur * 128 + f];
    atomicAdd(p + 0, acc.x); atomicAdd(p + 1, acc.y);
    atomicAdd(p + 2, acc.z); atomicAdd(p + 3, acc.w);
    if (lane == 0) atomicAdd(&counts[cur], cnt);
}

// ---------------- head: out[g] = dot(pooled[g], w_out)/count + b_out --------
__global__ __launch_bounds__(256) void out_kernel(const float* __restrict__ pooled,
                                                  const float* __restrict__ counts,
                                                  const float* __restrict__ w_out,
                                                  const float* __restrict__ b_out,
                                                  float* __restrict__ out) {
    int gph = threadIdx.x;   // one block of 256
    float c = fmaxf(counts[gph], 1.0f);
    float s = 0.0f;
    for (int f = 0; f < 128; ++f) s += pooled[gph * 128 + f] * w_out[f];
    out[gph] = s / c + b_out[0];
}

extern "C" void kernel_launch(void* const* d_in, const int* in_sizes, int n_in,
                              void* d_out, int out_size, void* d_ws, size_t ws_size,
                              hipStream_t stream) {
    const float* x     = (const float*)d_in[0];
    const int*   edge  = (const int*)d_in[1];   // [2, E]
    const int*   batch = (const int*)d_in[2];
    const float* w1    = (const float*)d_in[3];
    const float* b1    = (const float*)d_in[4];
    const float* w2    = (const float*)d_in[5];
    const float* b2    = (const float*)d_in[6];
    const float* w_out = (const float*)d_in[7];
    const float* b_out = (const float*)d_in[8];
    float* out = (float*)d_out;

    char* ws = (char*)d_ws;
    const size_t FEAT_BYTES = (size_t)N_NODES * 128 * 4;   // 51,200,000
    float* buf0   = (float*)ws;                              // H (x@W)
    float* buf1   = (float*)(ws + FEAT_BYTES);               // AGG / Y
    float* deg    = (float*)(ws + 2 * FEAT_BYTES);           // deg -> dinv
    float* pooled = (float*)(ws + 2 * FEAT_BYTES + 400000);  // [256,128]
    float* counts = (float*)(ws + 2 * FEAT_BYTES + 400000 + N_GRAPHS * 128 * 4);

    const int* src = edge;
    const int* dst = edge + N_EDGES;

    // zero-init accumulators
    hipMemsetAsync(deg, 0, N_NODES * 4, stream);
    hipMemsetAsync(buf1, 0, FEAT_BYTES, stream);
    hipMemsetAsync(pooled, 0, (N_GRAPHS * 128 + N_GRAPHS) * 4, stream);

    // degrees -> dinv
    deg_kernel<<<(N_EDGES + 255) / 256, 256, 0, stream>>>(dst, deg);
    dinv_kernel<<<(N_NODES + 255) / 256, 256, 0, stream>>>(deg);

    // ----- layer 1 -----
    gemm_kernel<<<N_NODES / GROWS, 256, 0, stream>>>(x, w1, buf0);
    scatter_kernel<<<(N_EDGES * 32) / 256, 256, 0, stream>>>(src, dst, deg, buf0, buf1);
    epilogue_kernel<<<(N_NODES * 32 + 255) / 256, 256, 0, stream>>>(buf0, deg, b1, buf1);

    // ----- layer 2 -----
    gemm_kernel<<<N_NODES / GROWS, 256, 0, stream>>>(buf1, w2, buf0);
    hipMemsetAsync(buf1, 0, FEAT_BYTES, stream);
    scatter_kernel<<<(N_EDGES * 32) / 256, 256, 0, stream>>>(src, dst, deg, buf0, buf1);
    epilogue_kernel<<<(N_NODES * 32 + 255) / 256, 256, 0, stream>>>(buf0, deg, b2, buf1);

    // ----- pool + head -----
    int ngroups = (N_NODES + NODES_PER_GROUP - 1) / NODES_PER_GROUP;
    pool_kernel<<<(ngroups * 32 + 255) / 256, 256, 0, stream>>>(buf1, batch, pooled, counts);
    out_kernel<<<1, 256, 0, stream>>>(pooled, counts, w_out, b_out, out);
}

// Round 2
// 746.035 us; speedup vs baseline: 7.7666x; 7.7666x over previous
//
#include <hip/hip_runtime.h>

#define N_NODES 100000
#define N_EDGES 1600000
#define N_GRAPHS 256

// ---------------- CSR build: histogram -> scan -> fill ----------------------
__global__ __launch_bounds__(256) void hist_kernel(const int* __restrict__ dst,
                                                   int* __restrict__ degi) {
    int e = blockIdx.x * 256 + threadIdx.x;
    if (e < N_EDGES) atomicAdd(&degi[dst[e]], 1);
}

#define SCHUNK 2048
__global__ __launch_bounds__(256) void scan1_kernel(const int* __restrict__ degi,
                                                    int* __restrict__ row_off,
                                                    int* __restrict__ chunk_sum) {
    __shared__ int tsum[256];
    int base = blockIdx.x * SCHUNK;
    int tid = threadIdx.x;
    int v[8];
    int s = 0;
#pragma unroll
    for (int j = 0; j < 8; ++j) {
        int idx = base + tid * 8 + j;
        v[j] = (idx < N_NODES) ? degi[idx] : 0;
        s += v[j];
    }
    tsum[tid] = s;
    __syncthreads();
    for (int off = 1; off < 256; off <<= 1) {
        int y = (tid >= off) ? tsum[tid - off] : 0;
        __syncthreads();
        tsum[tid] += y;
        __syncthreads();
    }
    int run = (tid > 0) ? tsum[tid - 1] : 0;
#pragma unroll
    for (int j = 0; j < 8; ++j) {
        int idx = base + tid * 8 + j;
        if (idx < N_NODES) row_off[idx] = run;
        run += v[j];
    }
    if (tid == 255) chunk_sum[blockIdx.x] = tsum[255];
}

__global__ void scan2_kernel(int* __restrict__ chunk_sum, int nchunks) {
    if (threadIdx.x == 0) {
        int run = 0;
        for (int i = 0; i < nchunks; ++i) {
            int t = chunk_sum[i];
            chunk_sum[i] = run;
            run += t;
        }
    }
}

__global__ __launch_bounds__(256) void scan3_kernel(int* __restrict__ row_off,
                                                    const int* __restrict__ chunk_sum) {
    int i = blockIdx.x * 256 + threadIdx.x;
    if (i < N_NODES) row_off[i] += chunk_sum[i >> 11];
}

__global__ __launch_bounds__(256) void dinv_kernel(const int* __restrict__ degi,
                                                   float* __restrict__ dinv) {
    int i = blockIdx.x * 256 + threadIdx.x;
    if (i < N_NODES) dinv[i] = rsqrtf((float)degi[i] + 1.0f);
}

__global__ __launch_bounds__(256) void fill_kernel(const int* __restrict__ src,
                                                   const int* __restrict__ dst,
                                                   int* __restrict__ cursor,
                                                   int* __restrict__ csr_src) {
    int e = blockIdx.x * 256 + threadIdx.x;
    if (e < N_EDGES) {
        int pos = atomicAdd(&cursor[dst[e]], 1);
        csr_src[pos] = src[e];
    }
}

// ---------------- GEMM: HT[N,128] = (X[N,128] @ W[128,128]) * dinv[row] -----
#define GROWS 16
__global__ __launch_bounds__(256) void gemm_kernel(const float* __restrict__ X,
                                                   const float* __restrict__ W,
                                                   const float* __restrict__ dinv,
                                                   float* __restrict__ HT) {
    __shared__ float Wl[64 * 128];
    __shared__ float Xl[GROWS * 132];
    const int tid = threadIdx.x;
    const int row0 = blockIdx.x * GROWS;

    for (int i = tid * 4; i < GROWS * 128; i += 256 * 4) {
        int r = i >> 7, k = i & 127;
        *(float4*)&Xl[r * 132 + k] = *(const float4*)&X[(row0 + r) * 128 + k];
    }

    const int r  = tid >> 4;          // 0..15
    const int c0 = (tid & 15) * 8;    // 0,8,...,120
    float acc[8];
#pragma unroll
    for (int i = 0; i < 8; ++i) acc[i] = 0.0f;

    for (int kb = 0; kb < 128; kb += 64) {
        __syncthreads();
        for (int i = tid * 4; i < 64 * 128; i += 256 * 4) {
            *(float4*)&Wl[i] = *(const float4*)&W[kb * 128 + i];
        }
        __syncthreads();
#pragma unroll 8
        for (int k = 0; k < 64; ++k) {
            float xv = Xl[r * 132 + kb + k];
            float4 wa = *(float4*)&Wl[k * 128 + c0];
            float4 wb = *(float4*)&Wl[k * 128 + c0 + 4];
            acc[0] += xv * wa.x; acc[1] += xv * wa.y;
            acc[2] += xv * wa.z; acc[3] += xv * wa.w;
            acc[4] += xv * wb.x; acc[5] += xv * wb.y;
            acc[6] += xv * wb.z; acc[7] += xv * wb.w;
        }
    }
    float di = dinv[row0 + r];
    float* o = &HT[(row0 + r) * 128 + c0];
    *(float4*)&o[0] = make_float4(acc[0] * di, acc[1] * di, acc[2] * di, acc[3] * di);
    *(float4*)&o[4] = make_float4(acc[4] * di, acc[5] * di, acc[6] * di, acc[7] * di);
}

// ---------------- gather: Y[n] = relu(dinv[n]*(sum ht[src] + ht[n]) + b) ----
// 32 threads per node, float4 per thread, register accumulation, no atomics.
__global__ __launch_bounds__(256) void gather_kernel(const int* __restrict__ row_off,
                                                     const int* __restrict__ csr_src,
                                                     const float* __restrict__ ht,
                                                     const float* __restrict__ dinv,
                                                     const float* __restrict__ b,
                                                     float* __restrict__ Y) {
    int t = blockIdx.x * 256 + threadIdx.x;
    int n = t >> 5;
    if (n >= N_NODES) return;
    int f = (t & 31) * 4;
    int e0 = row_off[n];
    int e1 = (n < N_NODES - 1) ? row_off[n + 1] : N_EDGES;
    float4 acc = *(const float4*)&ht[n * 128 + f];   // self-loop term
    for (int e = e0; e < e1; ++e) {
        int s = csr_src[e];
        float4 v = *(const float4*)&ht[s * 128 + f];
        acc.x += v.x; acc.y += v.y; acc.z += v.z; acc.w += v.w;
    }
    float di = dinv[n];
    float4 bb = *(const float4*)&b[f];
    float4 o;
    o.x = fmaxf(acc.x * di + bb.x, 0.0f);
    o.y = fmaxf(acc.y * di + bb.y, 0.0f);
    o.z = fmaxf(acc.z * di + bb.z, 0.0f);
    o.w = fmaxf(acc.w * di + bb.w, 0.0f);
    *(float4*)&Y[n * 128 + f] = o;
}

// ---------------- mean-pool: run-length accumulate over sorted batch --------
#define NODES_PER_GROUP 100
__global__ __launch_bounds__(256) void pool_kernel(const float* __restrict__ Y,
                                                   const int* __restrict__ batch,
                                                   float* __restrict__ pooled,
                                                   float* __restrict__ counts) {
    int g = (blockIdx.x * 256 + threadIdx.x) >> 5;
    int lane = threadIdx.x & 31;
    int f = lane * 4;
    int n0 = g * NODES_PER_GROUP;
    if (n0 >= N_NODES) return;
    int n1 = min(n0 + NODES_PER_GROUP, N_NODES);
    int cur = batch[n0];
    float4 acc = make_float4(0, 0, 0, 0);
    float cnt = 0.0f;
    for (int n = n0; n < n1; ++n) {
        int bid = batch[n];
        if (bid != cur) {
            float* p = &pooled[cur * 128 + f];
            atomicAdd(p + 0, acc.x); atomicAdd(p + 1, acc.y);
            atomicAdd(p + 2, acc.z); atomicAdd(p + 3, acc.w);
            if (lane == 0) atomicAdd(&counts[cur], cnt);
            acc = make_float4(0, 0, 0, 0); cnt = 0.0f; cur = bid;
        }
        float4 v = *(const float4*)&Y[n * 128 + f];
        acc.x += v.x; acc.y += v.y; acc.z += v.z; acc.w += v.w;
        cnt += 1.0f;
    }
    float* p = &pooled[cur * 128 + f];
    atomicAdd(p + 0, acc.x); atomicAdd(p + 1, acc.y);
    atomicAdd(p + 2, acc.z); atomicAdd(p + 3, acc.w);
    if (lane == 0) atomicAdd(&counts[cur], cnt);
}

// ---------------- head: out[g] = dot(pooled[g], w_out)/count + b_out --------
__global__ __launch_bounds__(256) void out_kernel(const float* __restrict__ pooled,
                                                  const float* __restrict__ counts,
                                                  const float* __restrict__ w_out,
                                                  const float* __restrict__ b_out,
                                                  float* __restrict__ out) {
    int gph = threadIdx.x;
    float c = fmaxf(counts[gph], 1.0f);
    float s = 0.0f;
    for (int f = 0; f < 128; ++f) s += pooled[gph * 128 + f] * w_out[f];
    out[gph] = s / c + b_out[0];
}

extern "C" void kernel_launch(void* const* d_in, const int* in_sizes, int n_in,
                              void* d_out, int out_size, void* d_ws, size_t ws_size,
                              hipStream_t stream) {
    const float* x     = (const float*)d_in[0];
    const int*   edge  = (const int*)d_in[1];   // [2, E]
    const int*   batch = (const int*)d_in[2];
    const float* w1    = (const float*)d_in[3];
    const float* b1    = (const float*)d_in[4];
    const float* w2    = (const float*)d_in[5];
    const float* b2    = (const float*)d_in[6];
    const float* w_out = (const float*)d_in[7];
    const float* b_out = (const float*)d_in[8];
    float* out = (float*)d_out;

    char* ws = (char*)d_ws;
    size_t off = 0;
    auto alloc = [&](size_t bytes) {
        void* p = ws + off;
        off += (bytes + 511) & ~(size_t)511;
        return p;
    };
    const size_t FEAT_BYTES = (size_t)N_NODES * 128 * 4;     // 51.2 MB
    float* buf0      = (float*)alloc(FEAT_BYTES);            // HT
    float* buf1      = (float*)alloc(FEAT_BYTES);            // Y
    int*   degi      = (int*)alloc(N_NODES * 4);
    float* dinv      = (float*)alloc(N_NODES * 4);
    int*   row_off   = (int*)alloc(N_NODES * 4);
    int*   cursor    = (int*)alloc(N_NODES * 4);
    int*   chunk_sum = (int*)alloc(1024);
    int*   csr_src   = (int*)alloc(N_EDGES * 4);             // 6.4 MB
    float* pooled    = (float*)alloc(N_GRAPHS * 128 * 4);
    float* counts    = (float*)alloc(N_GRAPHS * 4);

    const int* src = edge;
    const int* dst = edge + N_EDGES;

    hipMemsetAsync(degi, 0, N_NODES * 4, stream);
    hipMemsetAsync(pooled, 0, N_GRAPHS * 128 * 4, stream);
    hipMemsetAsync(counts, 0, N_GRAPHS * 4, stream);

    // ----- CSR build -----
    const int nchunks = (N_NODES + SCHUNK - 1) / SCHUNK;     // 49
    hist_kernel<<<(N_EDGES + 255) / 256, 256, 0, stream>>>(dst, degi);
    scan1_kernel<<<nchunks, 256, 0, stream>>>(degi, row_off, chunk_sum);
    scan2_kernel<<<1, 64, 0, stream>>>(chunk_sum, nchunks);
    scan3_kernel<<<(N_NODES + 255) / 256, 256, 0, stream>>>(row_off, chunk_sum);
    dinv_kernel<<<(N_NODES + 255) / 256, 256, 0, stream>>>(degi, dinv);
    hipMemcpyAsync(cursor, row_off, N_NODES * 4, hipMemcpyDeviceToDevice, stream);
    fill_kernel<<<(N_EDGES + 255) / 256, 256, 0, stream>>>(src, dst, cursor, csr_src);

    // ----- layer 1 -----
    gemm_kernel<<<N_NODES / GROWS, 256, 0, stream>>>(x, w1, dinv, buf0);
    gather_kernel<<<(N_NODES * 32 + 255) / 256, 256, 0, stream>>>(row_off, csr_src, buf0, dinv, b1, buf1);

    // ----- layer 2 -----
    gemm_kernel<<<N_NODES / GROWS, 256, 0, stream>>>(buf1, w2, dinv, buf0);
    gather_kernel<<<(N_NODES * 32 + 255) / 256, 256, 0, stream>>>(row_off, csr_src, buf0, dinv, b2, buf1);

    // ----- pool + head -----
    int ngroups = (N_NODES + NODES_PER_GROUP - 1) / NODES_PER_GROUP;
    pool_kernel<<<(ngroups * 32 + 255) / 256, 256, 0, stream>>>(buf1, batch, pooled, counts);
    out_kernel<<<1, 256, 0, stream>>>(pooled, counts, w_out, b_out, out);
}

// Round 3
// 602.156 us; speedup vs baseline: 9.6224x; 1.2389x over previous
//
#include <hip/hip_runtime.h>

#define N_NODES 100000
#define N_EDGES 1600000
#define N_GRAPHS 256

// ---------------- CSR build: histogram -> scan -> fill ----------------------
__global__ __launch_bounds__(256) void hist_kernel(const int* __restrict__ dst,
                                                   int* __restrict__ degi) {
    int e = blockIdx.x * 256 + threadIdx.x;
    if (e < N_EDGES) atomicAdd(&degi[dst[e]], 1);
}

#define SCHUNK 2048
__global__ __launch_bounds__(256) void scan1_kernel(const int* __restrict__ degi,
                                                    int* __restrict__ row_off,
                                                    int* __restrict__ chunk_sum) {
    __shared__ int tsum[256];
    int base = blockIdx.x * SCHUNK;
    int tid = threadIdx.x;
    int v[8];
    int s = 0;
#pragma unroll
    for (int j = 0; j < 8; ++j) {
        int idx = base + tid * 8 + j;
        v[j] = (idx < N_NODES) ? degi[idx] : 0;
        s += v[j];
    }
    tsum[tid] = s;
    __syncthreads();
    for (int off = 1; off < 256; off <<= 1) {
        int y = (tid >= off) ? tsum[tid - off] : 0;
        __syncthreads();
        tsum[tid] += y;
        __syncthreads();
    }
    int run = (tid > 0) ? tsum[tid - 1] : 0;
#pragma unroll
    for (int j = 0; j < 8; ++j) {
        int idx = base + tid * 8 + j;
        if (idx < N_NODES) row_off[idx] = run;
        run += v[j];
    }
    if (tid == 255) chunk_sum[blockIdx.x] = tsum[255];
}

__global__ void scan2_kernel(int* __restrict__ chunk_sum, int nchunks) {
    if (threadIdx.x == 0) {
        int run = 0;
        for (int i = 0; i < nchunks; ++i) {
            int t = chunk_sum[i];
            chunk_sum[i] = run;
            run += t;
        }
    }
}

__global__ __launch_bounds__(256) void scan3_kernel(int* __restrict__ row_off,
                                                    const int* __restrict__ chunk_sum) {
    int i = blockIdx.x * 256 + threadIdx.x;
    if (i < N_NODES) row_off[i] += chunk_sum[i >> 11];
}

__global__ __launch_bounds__(256) void dinv_kernel(const int* __restrict__ degi,
                                                   float* __restrict__ dinv) {
    int i = blockIdx.x * 256 + threadIdx.x;
    if (i < N_NODES) dinv[i] = rsqrtf((float)degi[i] + 1.0f);
}

__global__ __launch_bounds__(256) void fill_kernel(const int* __restrict__ src,
                                                   const int* __restrict__ dst,
                                                   int* __restrict__ cursor,
                                                   int* __restrict__ csr_src) {
    int e = blockIdx.x * 256 + threadIdx.x;
    if (e < N_EDGES) {
        int pos = atomicAdd(&cursor[dst[e]], 1);
        csr_src[pos] = src[e];
    }
}

// ---------------- GEMM: HT[N,128] = (X @ W) * dinv[row] ---------------------
// 128x128 tile per 256-thread block; 8x8 outputs/thread in four 4x4 quadrants
// (rows {4rg,64+4rg}, cols {4cg,64+4cg}) so compute-phase b128 LDS reads are
// <=2-way bank aliased (free). X staged k-major (Xt[k][row], stride 132).
#define BM 128
#define KC 32
__global__ __launch_bounds__(256) void gemm_kernel(const float* __restrict__ X,
                                                   const float* __restrict__ W,
                                                   const float* __restrict__ dinv,
                                                   float* __restrict__ HT) {
    __shared__ float Xt[KC][132];
    __shared__ float Wl[KC][128];
    const int tid = threadIdx.x;
    const int row0 = blockIdx.x * BM;
    const int cg = tid & 15;
    const int rg = tid >> 4;
    const int c_lo = cg * 4, r_lo = rg * 4;

    float acc[8][8];
#pragma unroll
    for (int i = 0; i < 8; ++i)
#pragma unroll
        for (int j = 0; j < 8; ++j) acc[i][j] = 0.0f;

    for (int kb = 0; kb < 128; kb += KC) {
        __syncthreads();
        // stage X^T: 128 rows x KC ks; coalesced float4 global reads,
        // transposed scalar LDS stores (stride 132 keeps them ~4-way max)
#pragma unroll
        for (int i = 0; i < 4; ++i) {
            int idx = tid * 4 + i * 1024;        // 0..4095
            int r = idx >> 5;
            int kk = idx & 31;
            int rr = row0 + r;
            if (rr >= N_NODES) rr = N_NODES - 1;
            const float4 v = *(const float4*)&X[(size_t)rr * 128 + kb + kk];
            Xt[kk + 0][r] = v.x;
            Xt[kk + 1][r] = v.y;
            Xt[kk + 2][r] = v.z;
            Xt[kk + 3][r] = v.w;
        }
        // stage W rows kb..kb+KC (row-major copy, coalesced)
#pragma unroll
        for (int i = 0; i < 4; ++i) {
            int idx = tid * 4 + i * 1024;
            int r = idx >> 7;
            int c = idx & 127;
            *(float4*)&Wl[r][c] = *(const float4*)&W[(size_t)(kb + r) * 128 + c];
        }
        __syncthreads();
#pragma unroll 4
        for (int k = 0; k < KC; ++k) {
            float4 a0 = *(float4*)&Xt[k][r_lo];
            float4 a1 = *(float4*)&Xt[k][64 + r_lo];
            float4 b0 = *(float4*)&Wl[k][c_lo];
            float4 b1 = *(float4*)&Wl[k][64 + c_lo];
            float a[8] = {a0.x, a0.y, a0.z, a0.w, a1.x, a1.y, a1.z, a1.w};
            float b[8] = {b0.x, b0.y, b0.z, b0.w, b1.x, b1.y, b1.z, b1.w};
#pragma unroll
            for (int i = 0; i < 8; ++i)
#pragma unroll
                for (int j = 0; j < 8; ++j)
                    acc[i][j] = fmaf(a[i], b[j], acc[i][j]);
        }
    }
    // epilogue: scale by dinv[row], write two float4s per row-slot
#pragma unroll
    for (int i = 0; i < 8; ++i) {
        int ri = (i < 4) ? (r_lo + i) : (64 + r_lo + i - 4);
        int rr = row0 + ri;
        if (rr < N_NODES) {
            float di = dinv[rr];
            float4 o0 = make_float4(acc[i][0] * di, acc[i][1] * di,
                                    acc[i][2] * di, acc[i][3] * di);
            float4 o1 = make_float4(acc[i][4] * di, acc[i][5] * di,
                                    acc[i][6] * di, acc[i][7] * di);
            *(float4*)&HT[(size_t)rr * 128 + c_lo] = o0;
            *(float4*)&HT[(size_t)rr * 128 + 64 + c_lo] = o1;
        }
    }
}

// ---------------- gather: Y[n] = relu(dinv[n]*(sum ht[src] + ht[n]) + b) ----
__global__ __launch_bounds__(256) void gather_kernel(const int* __restrict__ row_off,
                                                     const int* __restrict__ csr_src,
                                                     const float* __restrict__ ht,
                                                     const float* __restrict__ dinv,
                                                     const float* __restrict__ b,
                                                     float* __restrict__ Y) {
    int t = blockIdx.x * 256 + threadIdx.x;
    int n = t >> 5;
    if (n >= N_NODES) return;
    int f = (t & 31) * 4;
    int e0 = row_off[n];
    int e1 = (n < N_NODES - 1) ? row_off[n + 1] : N_EDGES;
    const float* htf = ht + f;
    float4 acc0 = *(const float4*)&htf[(size_t)n * 128];   // self-loop term
    float4 acc1 = make_float4(0, 0, 0, 0);
    int e = e0;
    for (; e + 2 <= e1; e += 2) {
        int s0 = csr_src[e];
        int s1 = csr_src[e + 1];
        float4 v0 = *(const float4*)&htf[(size_t)s0 * 128];
        float4 v1 = *(const float4*)&htf[(size_t)s1 * 128];
        acc0.x += v0.x; acc0.y += v0.y; acc0.z += v0.z; acc0.w += v0.w;
        acc1.x += v1.x; acc1.y += v1.y; acc1.z += v1.z; acc1.w += v1.w;
    }
    if (e < e1) {
        int s = csr_src[e];
        float4 v = *(const float4*)&htf[(size_t)s * 128];
        acc0.x += v.x; acc0.y += v.y; acc0.z += v.z; acc0.w += v.w;
    }
    float di = dinv[n];
    float4 bb = *(const float4*)&b[f];
    float4 o;
    o.x = fmaxf((acc0.x + acc1.x) * di + bb.x, 0.0f);
    o.y = fmaxf((acc0.y + acc1.y) * di + bb.y, 0.0f);
    o.z = fmaxf((acc0.z + acc1.z) * di + bb.z, 0.0f);
    o.w = fmaxf((acc0.w + acc1.w) * di + bb.w, 0.0f);
    *(float4*)&Y[(size_t)n * 128 + f] = o;
}

// ---------------- mean-pool: run-length accumulate over sorted batch --------
#define NODES_PER_GROUP 100
__global__ __launch_bounds__(256) void pool_kernel(const float* __restrict__ Y,
                                                   const int* __restrict__ batch,
                                                   float* __restrict__ pooled,
                                                   float* __restrict__ counts) {
    int g = (blockIdx.x * 256 + threadIdx.x) >> 5;
    int lane = threadIdx.x & 31;
    int f = lane * 4;
    int n0 = g * NODES_PER_GROUP;
    if (n0 >= N_NODES) return;
    int n1 = min(n0 + NODES_PER_GROUP, N_NODES);
    int cur = batch[n0];
    float4 acc = make_float4(0, 0, 0, 0);
    float cnt = 0.0f;
    for (int n = n0; n < n1; ++n) {
        int bid = batch[n];
        if (bid != cur) {
            float* p = &pooled[cur * 128 + f];
            atomicAdd(p + 0, acc.x); atomicAdd(p + 1, acc.y);
            atomicAdd(p + 2, acc.z); atomicAdd(p + 3, acc.w);
            if (lane == 0) atomicAdd(&counts[cur], cnt);
            acc = make_float4(0, 0, 0, 0); cnt = 0.0f; cur = bid;
        }
        float4 v = *(const float4*)&Y[(size_t)n * 128 + f];
        acc.x += v.x; acc.y += v.y; acc.z += v.z; acc.w += v.w;
        cnt += 1.0f;
    }
    float* p = &pooled[cur * 128 + f];
    atomicAdd(p + 0, acc.x); atomicAdd(p + 1, acc.y);
    atomicAdd(p + 2, acc.z); atomicAdd(p + 3, acc.w);
    if (lane == 0) atomicAdd(&counts[cur], cnt);
}

// ---------------- head: out[g] = dot(pooled[g], w_out)/count + b_out --------
__global__ __launch_bounds__(256) void out_kernel(const float* __restrict__ pooled,
                                                  const float* __restrict__ counts,
                                                  const float* __restrict__ w_out,
                                                  const float* __restrict__ b_out,
                                                  float* __restrict__ out) {
    int gph = threadIdx.x;
    float c = fmaxf(counts[gph], 1.0f);
    float s = 0.0f;
    for (int f = 0; f < 128; ++f) s += pooled[gph * 128 + f] * w_out[f];
    out[gph] = s / c + b_out[0];
}

extern "C" void kernel_launch(void* const* d_in, const int* in_sizes, int n_in,
                              void* d_out, int out_size, void* d_ws, size_t ws_size,
                              hipStream_t stream) {
    const float* x     = (const float*)d_in[0];
    const int*   edge  = (const int*)d_in[1];   // [2, E]
    const int*   batch = (const int*)d_in[2];
    const float* w1    = (const float*)d_in[3];
    const float* b1    = (const float*)d_in[4];
    const float* w2    = (const float*)d_in[5];
    const float* b2    = (const float*)d_in[6];
    const float* w_out = (const float*)d_in[7];
    const float* b_out = (const float*)d_in[8];
    float* out = (float*)d_out;

    char* ws = (char*)d_ws;
    size_t off = 0;
    auto alloc = [&](size_t bytes) {
        void* p = ws + off;
        off += (bytes + 511) & ~(size_t)511;
        return p;
    };
    const size_t FEAT_BYTES = (size_t)N_NODES * 128 * 4;     // 51.2 MB
    float* buf0      = (float*)alloc(FEAT_BYTES);            // HT
    float* buf1      = (float*)alloc(FEAT_BYTES);            // Y
    int*   degi      = (int*)alloc(N_NODES * 4);
    float* dinv      = (float*)alloc(N_NODES * 4);
    int*   row_off   = (int*)alloc(N_NODES * 4);
    int*   cursor    = (int*)alloc(N_NODES * 4);
    int*   chunk_sum = (int*)alloc(1024);
    int*   csr_src   = (int*)alloc(N_EDGES * 4);             // 6.4 MB
    float* pooled    = (float*)alloc(N_GRAPHS * 128 * 4);
    float* counts    = (float*)alloc(N_GRAPHS * 4);

    const int* src = edge;
    const int* dst = edge + N_EDGES;

    hipMemsetAsync(degi, 0, N_NODES * 4, stream);
    hipMemsetAsync(pooled, 0, N_GRAPHS * 128 * 4, stream);
    hipMemsetAsync(counts, 0, N_GRAPHS * 4, stream);

    // ----- CSR build -----
    const int nchunks = (N_NODES + SCHUNK - 1) / SCHUNK;     // 49
    hist_kernel<<<(N_EDGES + 255) / 256, 256, 0, stream>>>(dst, degi);
    scan1_kernel<<<nchunks, 256, 0, stream>>>(degi, row_off, chunk_sum);
    scan2_kernel<<<1, 64, 0, stream>>>(chunk_sum, nchunks);
    scan3_kernel<<<(N_NODES + 255) / 256, 256, 0, stream>>>(row_off, chunk_sum);
    dinv_kernel<<<(N_NODES + 255) / 256, 256, 0, stream>>>(degi, dinv);
    hipMemcpyAsync(cursor, row_off, N_NODES * 4, hipMemcpyDeviceToDevice, stream);
    fill_kernel<<<(N_EDGES + 255) / 256, 256, 0, stream>>>(src, dst, cursor, csr_src);

    // ----- layer 1 -----
    int gblocks = (N_NODES + BM - 1) / BM;
    gemm_kernel<<<gblocks, 256, 0, stream>>>(x, w1, dinv, buf0);
    gather_kernel<<<(N_NODES * 32 + 255) / 256, 256, 0, stream>>>(row_off, csr_src, buf0, dinv, b1, buf1);

    // ----- layer 2 -----
    gemm_kernel<<<gblocks, 256, 0, stream>>>(buf1, w2, dinv, buf0);
    gather_kernel<<<(N_NODES * 32 + 255) / 256, 256, 0, stream>>>(row_off, csr_src, buf0, dinv, b2, buf1);

    // ----- pool + head -----
    int ngroups = (N_NODES + NODES_PER_GROUP - 1) / NODES_PER_GROUP;
    pool_kernel<<<(ngroups * 32 + 255) / 256, 256, 0, stream>>>(buf1, batch, pooled, counts);
    out_kernel<<<1, 256, 0, stream>>>(pooled, counts, w_out, b_out, out);
}